// Round 1
// baseline (82.786 us; speedup 1.0000x reference)
//
#include <hip/hip_runtime.h>

#define BB 4
#define NN 512
#define FIN 128
#define HH 4
#define DD 32
#define HID 128
#define NOUT 384   // 128 src + 128 tgt + 128 res
#define MT 8
#define ITILE 16
#define LN_EPS 1e-5f
#define NEG 0.2f

__device__ __forceinline__ float leaky(float x){ return x > 0.f ? x : NEG*x; }

// Pack Wt[k][o]: o in [0,128)=W_src rows, [128,256)=W_tgt rows, [256,384)=W_res rows
__global__ void pack_w(const float* __restrict__ Wsrc, const float* __restrict__ Wtgt,
                       const float* __restrict__ Wres, float* __restrict__ Wt) {
    int idx = blockIdx.x * 256 + threadIdx.x;
    if (idx >= FIN * NOUT) return;
    int k = idx / NOUT, o = idx % NOUT;
    float v;
    if (o < 128)      v = Wsrc[o * FIN + k];
    else if (o < 256) v = Wtgt[(o - 128) * FIN + k];
    else              v = Wres[(o - 256) * FIN + k];
    Wt[idx] = v;
}

// Fused proj: Linear -> LayerNorm(32) -> LeakyReLU for src/tgt, Linear+bias+Leaky for res
__global__ __launch_bounds__(NOUT) void proj_kernel(
    const float* __restrict__ x, const float* __restrict__ Wt,
    const float* __restrict__ gsrc, const float* __restrict__ bsrc,
    const float* __restrict__ gtgt, const float* __restrict__ btgt,
    const float* __restrict__ bres,
    float* __restrict__ Usrc, float* __restrict__ Utgt, float* __restrict__ res)
{
    __shared__ float xs[MT * FIN];
    int tid = threadIdx.x;
    int r0 = blockIdx.x * MT;              // row over flattened [B*N]
    const float* base = x + (size_t)r0 * FIN;
    for (int idx = tid; idx < MT * FIN; idx += NOUT) xs[idx] = base[idx];
    __syncthreads();

    int o = tid;
    float acc[MT];
    #pragma unroll
    for (int m = 0; m < MT; m++) acc[m] = 0.f;
    for (int k = 0; k < FIN; k++) {
        float w = Wt[k * NOUT + o];
        #pragma unroll
        for (int m = 0; m < MT; m++) acc[m] = fmaf(w, xs[m * FIN + k], acc[m]);
    }

    float gg = 1.f, bb2 = 0.f, bres_v = 0.f;
    if (o < 128)      { gg = gsrc[o];       bb2 = bsrc[o]; }
    else if (o < 256) { gg = gtgt[o - 128]; bb2 = btgt[o - 128]; }
    else              { bres_v = bres[o - 256]; }

    #pragma unroll
    for (int m = 0; m < MT; m++) {
        int r = r0 + m;
        int b = r >> 9;            // /512
        int n = r & (NN - 1);
        float v = acc[m];
        if (o < 256) {
            // LayerNorm over the 32-feature group (lanes o..o|31, within half-wave)
            float s = v, sq = v * v;
            #pragma unroll
            for (int msk = 16; msk >= 1; msk >>= 1) {
                s  += __shfl_xor(s,  msk);
                sq += __shfl_xor(sq, msk);
            }
            float mean = s * (1.f / DD);
            float var  = sq * (1.f / DD) - mean * mean;
            float nv = (v - mean) * rsqrtf(var + LN_EPS);
            nv = leaky(nv * gg + bb2);
            int oo = o & 127;
            int h = oo >> 5, d = oo & 31;
            float* dst = (o < 128) ? Usrc : Utgt;
            dst[((size_t)(b * HH + h) * NN + n) * DD + d] = nv;
        } else {
            res[(size_t)r * HID + (o - 256)] = leaky(v + bres_v);
        }
    }
}

// Attention: one block per (b,h,i-tile of 16). U_tgt transposed in LDS.
__global__ __launch_bounds__(256) void attn_kernel(
    const float* __restrict__ Usrc, const float* __restrict__ Utgt,
    const float* __restrict__ attn, const float* __restrict__ res,
    float* __restrict__ out)
{
    __shared__ float tT[DD][NN + 1];       // pad: stride 513 -> conflict-free both axes
    __shared__ float p_lds[NN];
    __shared__ float s_lds[DD];
    __shared__ float redmax[4], redsum[4];
    __shared__ float part[8][DD + 1];

    int tid = threadIdx.x;
    int blk = blockIdx.x;
    int it = blk & 31;                     // N/ITILE = 32 tiles
    int h  = (blk >> 5) & 3;
    int b  = blk >> 7;

    const float* tgt_base = Utgt + (size_t)(b * HH + h) * NN * DD;
    const float* src_base = Usrc + (size_t)(b * HH + h) * NN * DD;

    // stage U_tgt[b,h] transposed
    for (int c = 0; c < NN * DD / 256; c++) {
        int idx = c * 256 + tid;
        int j = idx >> 5, d = idx & 31;
        tT[d][j] = tgt_base[idx];
    }

    const float scale = 0.17677669529663687f;  // 1/sqrt(32)
    float a_r[DD];
    #pragma unroll
    for (int d = 0; d < DD; d++) a_r[d] = attn[h * DD + d] * scale;

    int lane = tid & 63, wid = tid >> 6;
    int j0 = tid, j1 = tid + 256;
    __syncthreads();

    for (int ii = 0; ii < ITILE; ii++) {
        int i = it * ITILE + ii;
        if (tid < DD) s_lds[tid] = src_base[i * DD + tid];
        __syncthreads();                                   // S1: s ready
        float acc0 = 0.f, acc1 = 0.f;
        #pragma unroll
        for (int d = 0; d < DD; d++) {
            float sv = s_lds[d];
            acc0 = fmaf(a_r[d], leaky(sv + tT[d][j0]), acc0);
            acc1 = fmaf(a_r[d], leaky(sv + tT[d][j1]), acc1);
        }
        float m = fmaxf(acc0, acc1);
        #pragma unroll
        for (int msk = 32; msk >= 1; msk >>= 1) m = fmaxf(m, __shfl_xor(m, msk));
        if (lane == 0) redmax[wid] = m;
        __syncthreads();                                   // S2: max ready
        float mx = fmaxf(fmaxf(redmax[0], redmax[1]), fmaxf(redmax[2], redmax[3]));
        float p0 = __expf(acc0 - mx), p1 = __expf(acc1 - mx);
        p_lds[j0] = p0; p_lds[j1] = p1;
        float ps = p0 + p1;
        #pragma unroll
        for (int msk = 32; msk >= 1; msk >>= 1) ps += __shfl_xor(ps, msk);
        if (lane == 0) redsum[wid] = ps;
        __syncthreads();                                   // S3: p + sum ready
        float sum = (redsum[0] + redsum[1]) + (redsum[2] + redsum[3]);
        int d = tid & 31, c = tid >> 5;
        float acc = 0.f;
        int jb = c * 64;
        #pragma unroll 8
        for (int jj = 0; jj < 64; jj++)
            acc = fmaf(p_lds[jb + jj], tT[d][jb + jj], acc);
        part[c][d] = acc;
        __syncthreads();                                   // S4: partials ready
        if (tid < DD) {
            float v = 0.f;
            #pragma unroll
            for (int cc = 0; cc < 8; cc++) v += part[cc][tid];
            v /= sum;
            int r = b * NN + i;
            float rv = res[(size_t)r * HID + h * DD + tid];
            out[(size_t)r * HID + h * DD + tid] = fmaxf(v + rv, 0.f);
        }
    }
}

extern "C" void kernel_launch(void* const* d_in, const int* in_sizes, int n_in,
                              void* d_out, int out_size, void* d_ws, size_t ws_size,
                              hipStream_t stream) {
    const float* uf   = (const float*)d_in[0];
    const float* Wsrc = (const float*)d_in[1];
    const float* gsrc = (const float*)d_in[2];
    const float* bsrc = (const float*)d_in[3];
    const float* Wtgt = (const float*)d_in[4];
    const float* gtgt = (const float*)d_in[5];
    const float* btgt = (const float*)d_in[6];
    const float* attn = (const float*)d_in[7];
    const float* Wres = (const float*)d_in[8];
    const float* bres = (const float*)d_in[9];
    float* out = (float*)d_out;

    float* ws   = (float*)d_ws;
    float* Wt   = ws;                       // 128*384   = 49152
    float* Usrc = ws + 49152;               // 4*4*512*32 = 262144
    float* Utgt = Usrc + 262144;
    float* resb = Utgt + 262144;

    pack_w<<<(FIN * NOUT + 255) / 256, 256, 0, stream>>>(Wsrc, Wtgt, Wres, Wt);
    proj_kernel<<<(BB * NN) / MT, NOUT, 0, stream>>>(uf, Wt, gsrc, bsrc, gtgt, btgt,
                                                     bres, Usrc, Utgt, resb);
    attn_kernel<<<BB * HH * (NN / ITILE), 256, 0, stream>>>(Usrc, Utgt, attn, resb, out);
}

// Round 2
// 56.161 us; speedup vs baseline: 1.4741x; 1.4741x over previous
//
#include <hip/hip_runtime.h>

#define BB 4
#define NN 512
#define FIN 128
#define HH 4
#define DD 32
#define HID 128
#define NOUT 384   // 128 src + 128 tgt + 128 res
#define MT 8
#define ROWS 16
#define LN_EPS 1e-5f
#define NEG 0.2f

__device__ __forceinline__ float leaky(float x){ return x > 0.f ? x : NEG*x; }

// XOR-swizzled transposed-tgt index: logical (d, j) -> physical word in tT[32*512]
__device__ __forceinline__ int ttidx(int d, int j){ return d*NN + (j ^ ((d & 7) << 2)); }

// Pack Wt[k][o]: o in [0,128)=W_src rows, [128,256)=W_tgt rows, [256,384)=W_res rows
__global__ void pack_w(const float* __restrict__ Wsrc, const float* __restrict__ Wtgt,
                       const float* __restrict__ Wres, float* __restrict__ Wt) {
    int idx = blockIdx.x * 256 + threadIdx.x;
    if (idx >= FIN * NOUT) return;
    int k = idx / NOUT, o = idx % NOUT;
    float v;
    if (o < 128)      v = Wsrc[o * FIN + k];
    else if (o < 256) v = Wtgt[(o - 128) * FIN + k];
    else              v = Wres[(o - 256) * FIN + k];
    Wt[idx] = v;
}

// Fused proj: Linear -> LayerNorm(32) -> LeakyReLU for src/tgt, Linear+bias+Leaky for res
__global__ __launch_bounds__(NOUT) void proj_kernel(
    const float* __restrict__ x, const float* __restrict__ Wt,
    const float* __restrict__ gsrc, const float* __restrict__ bsrc,
    const float* __restrict__ gtgt, const float* __restrict__ btgt,
    const float* __restrict__ bres,
    float* __restrict__ Usrc, float* __restrict__ Utgt, float* __restrict__ res)
{
    __shared__ float xs[MT * FIN];
    int tid = threadIdx.x;
    int r0 = blockIdx.x * MT;              // row over flattened [B*N]
    const float* base = x + (size_t)r0 * FIN;
    for (int idx = tid; idx < MT * FIN; idx += NOUT) xs[idx] = base[idx];
    __syncthreads();

    int o = tid;
    float acc[MT];
    #pragma unroll
    for (int m = 0; m < MT; m++) acc[m] = 0.f;
    for (int k = 0; k < FIN; k++) {
        float w = Wt[k * NOUT + o];
        #pragma unroll
        for (int m = 0; m < MT; m++) acc[m] = fmaf(w, xs[m * FIN + k], acc[m]);
    }

    float gg = 1.f, bb2 = 0.f, bres_v = 0.f;
    if (o < 128)      { gg = gsrc[o];       bb2 = bsrc[o]; }
    else if (o < 256) { gg = gtgt[o - 128]; bb2 = btgt[o - 128]; }
    else              { bres_v = bres[o - 256]; }

    #pragma unroll
    for (int m = 0; m < MT; m++) {
        int r = r0 + m;
        int b = r >> 9;            // /512
        int n = r & (NN - 1);
        float v = acc[m];
        if (o < 256) {
            float s = v, sq = v * v;
            #pragma unroll
            for (int msk = 16; msk >= 1; msk >>= 1) {
                s  += __shfl_xor(s,  msk);
                sq += __shfl_xor(sq, msk);
            }
            float mean = s * (1.f / DD);
            float var  = sq * (1.f / DD) - mean * mean;
            float nv = (v - mean) * rsqrtf(var + LN_EPS);
            nv = leaky(nv * gg + bb2);
            int oo = o & 127;
            int hh = oo >> 5, d = oo & 31;
            float* dst = (o < 128) ? Usrc : Utgt;
            dst[((size_t)(b * HH + hh) * NN + n) * DD + d] = nv;
        } else {
            res[(size_t)r * HID + (o - 256)] = leaky(v + bres_v);
        }
    }
}

// Attention: one block per (b,h,i-tile of 16), all 16 rows batched per pass.
__global__ __launch_bounds__(256) void attn_kernel(
    const float* __restrict__ Usrc, const float* __restrict__ Utgt,
    const float* __restrict__ attn, const float* __restrict__ res,
    float* __restrict__ out)
{
    __shared__ float tT[DD * NN];          // 64 KB, transposed + XOR-swizzled columns
    __shared__ float s_lds[ROWS][DD];      // 2 KB
    __shared__ float a_lds[DD];
    __shared__ float wmax[ROWS][4];
    __shared__ float wsum[ROWS][4];
    __shared__ float p_lds[4][NN];         // 8 KB (4-row chunks)
    __shared__ float part[8][4][DD];       // 4 KB

    const int tid = threadIdx.x;
    const int blk = blockIdx.x;
    const int it = blk & 31;               // N/ROWS = 32 tiles
    const int h  = (blk >> 5) & 3;
    const int b  = blk >> 7;

    const float* tgt = Utgt + (size_t)(b * HH + h) * NN * DD;
    const float* src = Usrc + (size_t)(b * HH + h) * NN * DD + (size_t)(it * ROWS) * DD;

    // stage tgt transposed+swizzled (coalesced float4 global reads)
    #pragma unroll
    for (int cc = 0; cc < 16; cc++) {
        int idx = cc * 256 + tid;          // 0..4095 float4s
        int j = idx >> 3;
        int d0 = (idx & 7) << 2;
        float4 v = *(const float4*)(tgt + j * DD + d0);
        tT[ttidx(d0 + 0, j)] = v.x;
        tT[ttidx(d0 + 1, j)] = v.y;
        tT[ttidx(d0 + 2, j)] = v.z;
        tT[ttidx(d0 + 3, j)] = v.w;
    }
    if (tid < 128) {
        int r = tid >> 3, d0 = (tid & 7) << 2;
        *(float4*)&s_lds[r][d0] = *(const float4*)(src + r * DD + d0);
    }
    if (tid < DD) a_lds[tid] = attn[h * DD + tid] * 0.17677669529663687f; // a*SCALE
    __syncthreads();

    const int j0 = tid, j1 = tid + 256;

    // At[j] = 0.6 * sum_d a'_d * t[j][d]   (row term 0.6*<a,s_i> cancels in softmax)
    float At0 = 0.f, At1 = 0.f;
    #pragma unroll
    for (int d = 0; d < DD; d++) {
        float av = a_lds[d];
        At0 = fmaf(av, tT[ttidx(d, j0)], At0);
        At1 = fmaf(av, tT[ttidx(d, j1)], At1);
    }
    At0 *= 0.6f; At1 *= 0.6f;

    // e~[r][j] = At[j] + 0.4 * sum_d a'_d * |s[r][d] + t[j][d]|
    float acc0[ROWS], acc1[ROWS];
    #pragma unroll
    for (int r = 0; r < ROWS; r++) { acc0[r] = 0.f; acc1[r] = 0.f; }

    for (int dg = 0; dg < 8; dg++) {
        int d0 = dg << 2;
        float4 a4 = *(float4*)&a_lds[d0];
        float t00 = tT[ttidx(d0 + 0, j0)], t01 = tT[ttidx(d0 + 1, j0)],
              t02 = tT[ttidx(d0 + 2, j0)], t03 = tT[ttidx(d0 + 3, j0)];
        float t10 = tT[ttidx(d0 + 0, j1)], t11 = tT[ttidx(d0 + 1, j1)],
              t12 = tT[ttidx(d0 + 2, j1)], t13 = tT[ttidx(d0 + 3, j1)];
        #pragma unroll
        for (int r = 0; r < ROWS; r++) {
            float4 sv = *(float4*)&s_lds[r][d0];
            acc0[r] = fmaf(a4.x, fabsf(sv.x + t00), acc0[r]);
            acc0[r] = fmaf(a4.y, fabsf(sv.y + t01), acc0[r]);
            acc0[r] = fmaf(a4.z, fabsf(sv.z + t02), acc0[r]);
            acc0[r] = fmaf(a4.w, fabsf(sv.w + t03), acc0[r]);
            acc1[r] = fmaf(a4.x, fabsf(sv.x + t10), acc1[r]);
            acc1[r] = fmaf(a4.y, fabsf(sv.y + t11), acc1[r]);
            acc1[r] = fmaf(a4.z, fabsf(sv.z + t12), acc1[r]);
            acc1[r] = fmaf(a4.w, fabsf(sv.w + t13), acc1[r]);
        }
    }

    const int lane = tid & 63, wid = tid >> 6;
    #pragma unroll
    for (int r = 0; r < ROWS; r++) {
        acc0[r] = fmaf(0.4f, acc0[r], At0);
        acc1[r] = fmaf(0.4f, acc1[r], At1);
        float m = fmaxf(acc0[r], acc1[r]);
        #pragma unroll
        for (int msk = 32; msk >= 1; msk >>= 1) m = fmaxf(m, __shfl_xor(m, msk));
        if (lane == 0) wmax[r][wid] = m;
    }
    __syncthreads();                                   // B: wave maxima ready

    #pragma unroll
    for (int r = 0; r < ROWS; r++) {
        float m = fmaxf(fmaxf(wmax[r][0], wmax[r][1]), fmaxf(wmax[r][2], wmax[r][3]));
        acc0[r] = __expf(acc0[r] - m);                 // unnormalized p
        acc1[r] = __expf(acc1[r] - m);
        float s = acc0[r] + acc1[r];
        #pragma unroll
        for (int msk = 32; msk >= 1; msk >>= 1) s += __shfl_xor(s, msk);
        if (lane == 0) wsum[r][wid] = s;
    }
    #pragma unroll
    for (int r2 = 0; r2 < 4; r2++) { p_lds[r2][j0] = acc0[r2]; p_lds[r2][j1] = acc1[r2]; }
    __syncthreads();                                   // B: sums + p chunk0 ready

    const int dd = tid & 31, cj = tid >> 5, jb = cj << 6;
    #pragma unroll
    for (int rc = 0; rc < 4; rc++) {
        float ag0 = 0.f, ag1 = 0.f, ag2 = 0.f, ag3 = 0.f;
        #pragma unroll
        for (int g = 0; g < 16; g++) {
            int col = jb + (g << 2);
            float4 tv  = *(float4*)&tT[dd * NN + (col ^ ((dd & 7) << 2))];
            float4 p0v = *(float4*)&p_lds[0][col];
            float4 p1v = *(float4*)&p_lds[1][col];
            float4 p2v = *(float4*)&p_lds[2][col];
            float4 p3v = *(float4*)&p_lds[3][col];
            ag0 = fmaf(tv.x, p0v.x, fmaf(tv.y, p0v.y, fmaf(tv.z, p0v.z, fmaf(tv.w, p0v.w, ag0))));
            ag1 = fmaf(tv.x, p1v.x, fmaf(tv.y, p1v.y, fmaf(tv.z, p1v.z, fmaf(tv.w, p1v.w, ag1))));
            ag2 = fmaf(tv.x, p2v.x, fmaf(tv.y, p2v.y, fmaf(tv.z, p2v.z, fmaf(tv.w, p2v.w, ag2))));
            ag3 = fmaf(tv.x, p3v.x, fmaf(tv.y, p3v.y, fmaf(tv.z, p3v.z, fmaf(tv.w, p3v.w, ag3))));
        }
        part[cj][0][dd] = ag0;
        part[cj][1][dd] = ag1;
        part[cj][2][dd] = ag2;
        part[cj][3][dd] = ag3;
        __syncthreads();                               // B: part ready, p consumed

        if (rc < 3) {                                  // refill p for next chunk
            #pragma unroll
            for (int r2 = 0; r2 < 4; r2++) {
                p_lds[r2][j0] = acc0[(rc + 1) * 4 + r2];
                p_lds[r2][j1] = acc1[(rc + 1) * 4 + r2];
            }
        }
        if (tid < 128) {                               // epilogue for this chunk
            int r2 = tid >> 5, d2 = tid & 31;
            float v = 0.f;
            #pragma unroll
            for (int c8 = 0; c8 < 8; c8++) v += part[c8][r2][d2];
            int r = rc * 4 + r2;
            float sum = (wsum[r][0] + wsum[r][1]) + (wsum[r][2] + wsum[r][3]);
            v /= sum;
            int i = it * ROWS + r;
            size_t row = (size_t)b * NN + i;
            float rv = res[row * HID + h * DD + d2];
            out[row * HID + h * DD + d2] = fmaxf(v + rv, 0.f);
        }
        if (rc < 3) __syncthreads();                   // B: p next chunk ready
    }
}

extern "C" void kernel_launch(void* const* d_in, const int* in_sizes, int n_in,
                              void* d_out, int out_size, void* d_ws, size_t ws_size,
                              hipStream_t stream) {
    const float* uf   = (const float*)d_in[0];
    const float* Wsrc = (const float*)d_in[1];
    const float* gsrc = (const float*)d_in[2];
    const float* bsrc = (const float*)d_in[3];
    const float* Wtgt = (const float*)d_in[4];
    const float* gtgt = (const float*)d_in[5];
    const float* btgt = (const float*)d_in[6];
    const float* attn = (const float*)d_in[7];
    const float* Wres = (const float*)d_in[8];
    const float* bres = (const float*)d_in[9];
    float* out = (float*)d_out;

    float* ws   = (float*)d_ws;
    float* Wt   = ws;                       // 128*384   = 49152
    float* Usrc = ws + 49152;               // 4*4*512*32 = 262144
    float* Utgt = Usrc + 262144;
    float* resb = Utgt + 262144;

    pack_w<<<(FIN * NOUT + 255) / 256, 256, 0, stream>>>(Wsrc, Wtgt, Wres, Wt);
    proj_kernel<<<(BB * NN) / MT, NOUT, 0, stream>>>(uf, Wt, gsrc, bsrc, gtgt, btgt,
                                                     bres, Usrc, Utgt, resb);
    attn_kernel<<<BB * HH * (NN / ROWS), 256, 0, stream>>>(Usrc, Utgt, attn, resb, out);
}